// Round 3
// baseline (9308.820 us; speedup 1.0000x reference)
//
#include <hip/hip_runtime.h>

typedef __attribute__((ext_vector_type(8))) short short8;
typedef __attribute__((ext_vector_type(4))) float floatx4;

#define BB 2048   // batch
#define SS 24     // seq len (src and tgt)
#define HH 1024   // hidden
#define VV 37     // vocab
#define EE 256    // embed
#define G4H 4096  // 4*H gates
#define OSTR (SS * VV)   // out row stride = 888

__device__ __forceinline__ unsigned short f2bf(float f) {
    union { float f; unsigned u; } x; x.f = f;
    unsigned r = x.u + 0x7FFF + ((x.u >> 16) & 1);   // RNE
    return (unsigned short)(r >> 16);
}
__device__ __forceinline__ float bf2f(unsigned short s) {
    union { unsigned u; float f; } x; x.u = ((unsigned)s) << 16; return x.f;
}
__device__ __forceinline__ float sigm(float x) {
    x = fminf(fmaxf(x, -15.f), 15.f);
    return 1.f / (1.f + __expf(-x));
}
__device__ __forceinline__ float tanh_(float x) {
    x = fminf(fmaxf(x, -15.f), 15.f);
    float e = __expf(2.f * x);
    return (e - 1.f) / (e + 1.f);
}

// permuted W row C <- original row: gate g=(C>>4)&3 (i,f,g,o), unit u=(C>>6)*16+(C&15)
__device__ __forceinline__ int wrow_orig(int C) {
    return (((C >> 4) & 3) << 10) | ((C >> 6) << 4) | (C & 15);
}

// async global->LDS DMA, 16B/lane; LDS dest = wave-uniform base + lane*16 [m97/m104]
typedef const __attribute__((address_space(1))) void* gas_t;
typedef __attribute__((address_space(3))) void* las_t;
__device__ __forceinline__ void gl_lds16(const void* g, void* l) {
    __builtin_amdgcn_global_load_lds((gas_t)g, (las_t)l, 16, 0, 0);
}

// ---------------- fp32 -> bf16 plain conversion (fcW) ----------------
__global__ __launch_bounds__(256)
void cvt_f2b_kernel(const float* __restrict__ s, unsigned short* __restrict__ d, int n4) {
    int i = blockIdx.x * 256 + threadIdx.x;
    if (i >= n4) return;
    float4 v = reinterpret_cast<const float4*>(s)[i];
    ushort4 o;
    o.x = f2bf(v.x); o.y = f2bf(v.y); o.z = f2bf(v.z); o.w = f2bf(v.w);
    reinterpret_cast<ushort4*>(d)[i] = o;
}

// ------- fp32 -> bf16 with gate-in-16-col-group permutation (K=1024 weights) -------
__global__ __launch_bounds__(256)
void cvt_perm_kernel(const float* __restrict__ s, unsigned short* __restrict__ d) {
    int i = blockIdx.x * 256 + threadIdx.x;     // over 4096 * 256 float4 groups
    int C  = i >> 8;                            // out row 0..4095
    int kk = i & 255;
    float4 v = reinterpret_cast<const float4*>(s)[(size_t)wrow_orig(C) * 256 + kk];
    ushort4 o;
    o.x = f2bf(v.x); o.y = f2bf(v.y); o.z = f2bf(v.z); o.w = f2bf(v.w);
    reinterpret_cast<ushort4*>(d)[(size_t)i] = o;
}

// ---------------- zero init (h0a,h1a bf16 + c0,c1 fp32 region, 24 MiB) ----------------
__global__ __launch_bounds__(256) void zero16_kernel(uint4* __restrict__ p) {
    uint4 z; z.x = 0; z.y = 0; z.z = 0; z.w = 0;
    p[(size_t)blockIdx.x * 256 + threadIdx.x] = z;
}

// ---------------- token matrix [2,S,B] ----------------
__global__ __launch_bounds__(256)
void tok_kernel(const int* __restrict__ src, const int* __restrict__ tgt, int* __restrict__ toks) {
    int idx = blockIdx.x * 256 + threadIdx.x;   // 2*24*2048
    int b  = idx & 2047;
    int st = idx >> 11;
    int tok;
    if (st < SS) tok = src[b * SS + st];
    else { int t = st - SS; tok = (t == 0) ? 1 : tgt[b * SS + (t - 1)]; }
    toks[idx] = tok;
}

// ---------------- per-layer bias sums, permuted layout ----------------
__global__ __launch_bounds__(256) void bias_sum_kernel(
        const float* e0i, const float* e0h, const float* e1i, const float* e1h,
        const float* d0i, const float* d0h, const float* d1i, const float* d1h,
        float* __restrict__ out) {
    int idx = blockIdx.x * 256 + threadIdx.x;   // 4*4096
    int layer = idx >> 12, C = idx & 4095;
    int src_j = wrow_orig(C);
    const float* pi; const float* ph;
    switch (layer) {
        case 0:  pi = e0i; ph = e0h; break;
        case 1:  pi = e1i; ph = e1h; break;
        case 2:  pi = d0i; ph = d0h; break;
        default: pi = d1i; ph = d1h; break;
    }
    out[idx] = pi[src_j] + ph[src_j];
}

// ---------------- fp32 input-projection tables: proj[table][v][C] ----------------
__global__ __launch_bounds__(256)
void proj_kernel(const float* __restrict__ emb, const float* __restrict__ eWih,
                 const float* __restrict__ dWih, float* __restrict__ proj) {
    // grid = 2 tables * 37 v * 16 C-blocks = 1184
    int bid = blockIdx.x;
    int table = bid / (VV * 16);
    int rem   = bid - table * (VV * 16);
    int v     = rem >> 4;
    int cblk  = rem & 15;
    const float* W = table ? dWih : eWih;
    __shared__ float es[EE];
    es[threadIdx.x] = emb[v * EE + threadIdx.x];
    __syncthreads();
    int C = (cblk << 8) + threadIdx.x;
    const float* wr = W + (size_t)wrow_orig(C) * EE;
    float acc = 0.f;
#pragma unroll 8
    for (int k = 0; k < EE; ++k) acc += es[k] * wr[k];
    proj[((size_t)table * VV + v) * G4H + C] = acc;
}

// ---------------- fused step kernel ----------------
// role 0 (L1, 1024 blks): gates1 = h1prev @ W_hh1^T + h0cur @ W_ih1^T + bias1 -> c1,h1out
//   128x64 tile, 64 chunks of BK=32 (A/W source switch at t=32).
// role 1 (L0, 512 blks): gates0 = h0cur @ W_hh0^T + proj[tok] + bias0 -> c0,h0out
//   two sequential 128x64 n-tiles, 64 chunks, mid-loop epilogue at t=32.
// role 2 (FC): logits for one decoder step.
// Inner loop: r0-proven simple structure (stage -> sync -> ds_read+MFMA -> sync),
// latency hidden by TLP: 12 KB LDS + small acc => 6 blocks/CU.
__global__ __launch_bounds__(256, 6)
void fused_step(
    const unsigned short* __restrict__ A10, const unsigned short* __restrict__ W10,
    const unsigned short* __restrict__ A11, const unsigned short* __restrict__ W11,
    const float* __restrict__ bias1, float* __restrict__ c1, unsigned short* __restrict__ h1out,
    const unsigned short* __restrict__ A00, const unsigned short* __restrict__ W00,
    const float* __restrict__ bias0, const float* __restrict__ proj0, const int* __restrict__ tok0,
    float* __restrict__ c0, unsigned short* __restrict__ h0out,
    const unsigned short* __restrict__ fcH, const unsigned short* __restrict__ fcWb,
    const float* __restrict__ fcb, float* __restrict__ fcOut,
    int nblk1, int nblk0, int nfc)
{
    __shared__ __align__(16) unsigned short As[4096];  // 128x32 bf16 = 8 KB
    __shared__ __align__(16) unsigned short Bs[2048];  // 64x32 bf16  = 4 KB

    const int nwg = gridDim.x;                 // always a multiple of 8
    const int bid = blockIdx.x;
    const int wg  = (bid & 7) * (nwg >> 3) + (bid >> 3);   // bijective XCD swizzle

    const int tid  = threadIdx.x;
    const int lane = tid & 63;
    const int wave = tid >> 6;
    const int g01  = nblk1 + nblk0;

    if (wg >= g01) {
        // ---- FC role: 8 batch rows per block, lane<37 = vocab col ----
        const int idx = wg - g01;
        if (lane >= VV) return;
        const unsigned short* wrow = fcWb + (size_t)lane * HH;
        const float bv = fcb[lane];
        const int b0 = (idx << 3) + (wave << 1);
#pragma unroll
        for (int rr = 0; rr < 2; ++rr) {
            const unsigned short* hrow = fcH + (size_t)(b0 + rr) * HH;
            float acc = bv;
#pragma unroll 4
            for (int k8 = 0; k8 < HH / 8; ++k8) {
                short8 hv = *reinterpret_cast<const short8*>(hrow + k8 * 8);
                short8 wv = *reinterpret_cast<const short8*>(wrow + k8 * 8);
#pragma unroll
                for (int uu = 0; uu < 8; ++uu)
                    acc += bf2f((unsigned short)hv[uu]) * bf2f((unsigned short)wv[uu]);
            }
            fcOut[(size_t)(b0 + rr) * OSTR + lane] = acc;
        }
        return;
    }

    const int role = (wg < nblk1) ? 0 : 1;
    const int idx  = role ? (wg - nblk1) : wg;
    const int m0 = (idx & 15) << 7;                        // 16 m-tiles of 128 rows
    const int n0 = role ? ((idx >> 4) << 7)                // role1: 32 pairs of 2x64 cols
                        : ((idx >> 4) << 6);               // role0: 64 tiles of 64 cols

    const unsigned short *pA0, *pA1, *pW0, *pW1;
    const float *bias, *prj; const int* tok;
    float* cst; unsigned short* hout;
    if (role == 0) {
        pA0 = A10; pA1 = A11; pW0 = W10; pW1 = W11;        // seg switch at t=32
        bias = bias1; prj = nullptr; tok = nullptr; cst = c1; hout = h1out;
    } else {
        pA0 = A00; pA1 = A00;
        pW0 = W00; pW1 = W00 + (size_t)64 * HH;            // n-tile switch at t=32
        bias = bias0; prj = proj0; tok = tok0; cst = c0; hout = h0out;
    }

    const int r16  = lane & 15;
    const int koff = (lane >> 4) << 3;
    const unsigned aoff0 = (unsigned)(m0 + (wave << 5) + r16) * HH + koff;  // rows wave*32..
    const unsigned aoff1 = aoff0 + (unsigned)(16 * HH);
    const unsigned woff  = (unsigned)(n0 + (wave << 4) + r16) * HH + koff;  // W rows (gate cols)
    const int q = lane >> 4;

    floatx4 acc[2][4];
#pragma unroll
    for (int i = 0; i < 2; ++i)
#pragma unroll
        for (int j = 0; j < 4; ++j)
            acc[i][j] = (floatx4){0.f, 0.f, 0.f, 0.f};

    // in-register LSTM cell epilogue for the 64-col tile at n0c
    auto epi = [&](int n0c) {
        const int ub = ((n0c >> 6) << 4) + r16;            // hidden unit for this lane
        float bj[4];
#pragma unroll
        for (int j = 0; j < 4; ++j)
            bj[j] = bias[n0c + (j << 4) + r16];
#pragma unroll
        for (int i = 0; i < 2; ++i) {
#pragma unroll
            for (int p = 0; p < 4; ++p) {
                const int row = m0 + (wave << 5) + (i << 4) + (q << 2) + p;
                float g0 = acc[i][0][p] + bj[0];
                float g1 = acc[i][1][p] + bj[1];
                float g2 = acc[i][2][p] + bj[2];
                float g3 = acc[i][3][p] + bj[3];
                if (role == 1) {
                    const float* pr = prj + (size_t)tok[row] * G4H + n0c + r16;
                    g0 += pr[0]; g1 += pr[16]; g2 += pr[32]; g3 += pr[48];
                }
                const float iv = sigm(g0);
                const float fv = sigm(g1);
                const float gv = tanh_(g2);
                const float ov = sigm(g3);
                const size_t ci = (size_t)row * HH + ub;
                const float cc = fv * cst[ci] + iv * gv;
                cst[ci] = cc;
                hout[ci] = f2bf(ov * tanh_(cc));
            }
        }
    };

#pragma unroll 1
    for (int t = 0; t < 64; ++t) {
        if (role == 1 && t == 32) {
            epi(n0);                        // n-tile 0 done (chunks 0..31)
#pragma unroll
            for (int i = 0; i < 2; ++i)
#pragma unroll
                for (int j = 0; j < 4; ++j)
                    acc[i][j] = (floatx4){0.f, 0.f, 0.f, 0.f};
        }
        const unsigned short* Ap = (t & 32) ? pA1 : pA0;
        const unsigned short* Wp = (t & 32) ? pW1 : pW0;
        const unsigned kk = (unsigned)(t & 31) << 5;
        gl_lds16(Ap + aoff0 + kk, As + (wave << 10));
        gl_lds16(Ap + aoff1 + kk, As + (wave << 10) + 512);
        gl_lds16(Wp + woff  + kk, Bs + (wave << 9));
        __syncthreads();                    // drains vmcnt(0): staged data visible

        const short8 af0 = *reinterpret_cast<const short8*>(As + (wave << 10) + (lane << 3));
        const short8 af1 = *reinterpret_cast<const short8*>(As + (wave << 10) + 512 + (lane << 3));
#pragma unroll
        for (int j = 0; j < 4; ++j) {
            const short8 bj = *reinterpret_cast<const short8*>(Bs + (j << 9) + (lane << 3));
            acc[0][j] = __builtin_amdgcn_mfma_f32_16x16x32_bf16(af0, bj, acc[0][j], 0, 0, 0);
            acc[1][j] = __builtin_amdgcn_mfma_f32_16x16x32_bf16(af1, bj, acc[1][j], 0, 0, 0);
        }
        __syncthreads();                    // readers done before next stage overwrites
    }

    epi(role ? (n0 + 64) : n0);
}

extern "C" void kernel_launch(void* const* d_in, const int* in_sizes, int n_in,
                              void* d_out, int out_size, void* d_ws, size_t ws_size,
                              hipStream_t stream) {
    const int*   src    = (const int*)d_in[0];
    const int*   tgt    = (const int*)d_in[1];
    const float* emb    = (const float*)d_in[2];
    const float* eW_ih0 = (const float*)d_in[3];
    const float* eW_hh0 = (const float*)d_in[4];
    const float* eb_ih0 = (const float*)d_in[5];
    const float* eb_hh0 = (const float*)d_in[6];
    const float* eW_ih1 = (const float*)d_in[7];
    const float* eW_hh1 = (const float*)d_in[8];
    const float* eb_ih1 = (const float*)d_in[9];
    const float* eb_hh1 = (const float*)d_in[10];
    const float* dW_ih0 = (const float*)d_in[11];
    const float* dW_hh0 = (const float*)d_in[12];
    const float* db_ih0 = (const float*)d_in[13];
    const float* db_hh0 = (const float*)d_in[14];
    const float* dW_ih1 = (const float*)d_in[15];
    const float* dW_hh1 = (const float*)d_in[16];
    const float* db_ih1 = (const float*)d_in[17];
    const float* db_hh1 = (const float*)d_in[18];
    const float* fcW    = (const float*)d_in[19];
    const float* fcb    = (const float*)d_in[20];
    float* out = (float*)d_out;

    // ---- workspace layout ----
    char* w = (char*)d_ws;
    size_t off = 0;
    auto walloc = [&](size_t bytes) { void* p = w + off; off += (bytes + 255) & ~(size_t)255; return p; };
    unsigned short* bW[8];
    const float* srcW[8] = {eW_ih0, eW_hh0, eW_ih1, eW_hh1, dW_ih0, dW_hh0, dW_ih1, dW_hh1};
    const int     szW[8] = {G4H*EE, G4H*HH, G4H*HH, G4H*HH, G4H*EE, G4H*HH, G4H*HH, G4H*HH};
    for (int i = 0; i < 8; ++i) bW[i] = (unsigned short*)walloc((size_t)szW[i] * 2);
    unsigned short* bfcW = (unsigned short*)walloc((size_t)VV * HH * 2);
    // zero region: h0a, h1a (bf16) + c0, c1 (fp32) — contiguous 24 MiB
    unsigned short* h0a = (unsigned short*)walloc((size_t)BB * HH * 2);
    unsigned short* h1a = (unsigned short*)walloc((size_t)BB * HH * 2);
    float* c0 = (float*)walloc((size_t)BB * HH * 4);
    float* c1 = (float*)walloc((size_t)BB * HH * 4);
    unsigned short* h0b = (unsigned short*)walloc((size_t)BB * HH * 2);
    unsigned short* h1b = (unsigned short*)walloc((size_t)BB * HH * 2);
    float* bsum = (float*)walloc((size_t)4 * G4H * 4);
    int*   toks = (int*)walloc((size_t)2 * SS * BB * 4);
    float* proj = (float*)walloc((size_t)2 * VV * G4H * 4);

    unsigned short* h0[2] = {h0a, h0b};
    unsigned short* h1[2] = {h1a, h1b};

    // ---- setup: permuted weights (K=1024 only; W_ih0 via proj), biases, tokens ----
    for (int i = 0; i < 8; ++i) {
        if (i == 0 || i == 4) continue;               // eW_ih0/dW_ih0: replaced by proj tables
        cvt_perm_kernel<<<(szW[i] / 4) / 256, 256, 0, stream>>>(srcW[i], bW[i]);
    }
    cvt_f2b_kernel<<<(VV * HH / 4 + 255) / 256, 256, 0, stream>>>(fcW, bfcW, VV * HH / 4);
    zero16_kernel<<<6144, 256, 0, stream>>>((uint4*)h0a);
    bias_sum_kernel<<<64, 256, 0, stream>>>(eb_ih0, eb_hh0, eb_ih1, eb_hh1,
                                            db_ih0, db_hh0, db_ih1, db_hh1, bsum);
    tok_kernel<<<384, 256, 0, stream>>>(src, tgt, toks);
    proj_kernel<<<2 * VV * 16, 256, 0, stream>>>(emb, eW_ih0, dW_ih0, proj);

    auto L0W = [&](int s) { return s < SS ? bW[1] : bW[5]; };   // W_hh0
    auto L1Wh = [&](int s) { return s < SS ? bW[3] : bW[7]; };  // W_hh1
    auto L1Wi = [&](int s) { return s < SS ? bW[2] : bW[6]; };  // W_ih1
    auto B0 = [&](int s) { return bsum + (size_t)(s < SS ? 0 : 2) * G4H; };
    auto B1 = [&](int s) { return bsum + (size_t)(s < SS ? 1 : 3) * G4H; };
    auto PJ = [&](int s) { return proj + (size_t)(s < SS ? 0 : 1) * VV * G4H; };

    // launch -1: layer0 step 0 only (reads zeros, writes h0[1]); 512 role-1 blocks
    fused_step<<<512, 256, 0, stream>>>(
        nullptr, nullptr, nullptr, nullptr, nullptr, nullptr, nullptr,
        h0[0], L0W(0), B0(0), PJ(0), toks, c0, h0[1],
        nullptr, nullptr, nullptr, nullptr,
        0, 512, 0);

    // fused launches X_s = layer1^s || layer0^{s+1} || fc^{s-1}(if decoder)
    for (int s = 0; s <= 46; ++s) {
        const int pb = s & 1;
        const int hasfc = (s >= SS + 1) ? 1 : 0;      // fc for decoder step t = s-25
        const unsigned short* fch = hasfc ? h1[pb] : nullptr;
        float* fco = hasfc ? (out + (size_t)(s - SS - 1) * VV) : nullptr;
        fused_step<<<1536 + (hasfc ? 256 : 0), 256, 0, stream>>>(
            h1[pb], L1Wh(s), h0[pb ^ 1], L1Wi(s), B1(s), c1, h1[pb ^ 1],
            h0[pb ^ 1], L0W(s + 1), B0(s + 1), PJ(s + 1), toks + (size_t)(s + 1) * BB, c0, h0[pb],
            fch, bfcW, fcb, fco,
            1024, 512, hasfc ? 256 : 0);
    }

    // launch 47: layer1^47 + fc^46   (pb = 1)
    fused_step<<<1280, 256, 0, stream>>>(
        h1[1], L1Wh(47), h0[0], L1Wi(47), B1(47), c1, h1[0],
        nullptr, nullptr, nullptr, nullptr, nullptr, nullptr, nullptr,
        h1[1], bfcW, fcb, out + (size_t)22 * VV,
        1024, 0, 256);

    // final: fc^47 (h1^47 lives in h1[0])
    fused_step<<<256, 256, 0, stream>>>(
        nullptr, nullptr, nullptr, nullptr, nullptr, nullptr, nullptr,
        nullptr, nullptr, nullptr, nullptr, nullptr, nullptr, nullptr,
        h1[0], bfcW, fcb, out + (size_t)23 * VV,
        0, 0, 256);
}

// Round 4
// 6318.401 us; speedup vs baseline: 1.4733x; 1.4733x over previous
//
#include <hip/hip_runtime.h>

typedef __attribute__((ext_vector_type(8))) short short8;
typedef __attribute__((ext_vector_type(4))) float floatx4;

#define BB 2048   // batch
#define SS 24     // seq len (src and tgt)
#define HH 1024   // hidden
#define VV 37     // vocab
#define EE 256    // embed
#define G4H 4096  // 4*H gates
#define OSTR (SS * VV)   // out row stride = 888

__device__ __forceinline__ unsigned short f2bf(float f) {
    union { float f; unsigned u; } x; x.f = f;
    unsigned r = x.u + 0x7FFF + ((x.u >> 16) & 1);   // RNE
    return (unsigned short)(r >> 16);
}
__device__ __forceinline__ float bf2f(unsigned short s) {
    union { unsigned u; float f; } x; x.u = ((unsigned)s) << 16; return x.f;
}
__device__ __forceinline__ float sigm(float x) {
    x = fminf(fmaxf(x, -15.f), 15.f);
    return 1.f / (1.f + __expf(-x));
}
__device__ __forceinline__ float tanh_(float x) {
    x = fminf(fmaxf(x, -15.f), 15.f);
    float e = __expf(2.f * x);
    return (e - 1.f) / (e + 1.f);
}

// permuted W row C <- original row: gate g=(C>>4)&3 (i,f,g,o), unit u=(C>>6)*16+(C&15)
__device__ __forceinline__ int wrow_orig(int C) {
    return (((C >> 4) & 3) << 10) | ((C >> 6) << 4) | (C & 15);
}

// async global->LDS DMA, 16B/lane; LDS dest = wave-uniform base + lane*16 [m97/m104]
typedef const __attribute__((address_space(1))) void* gas_t;
typedef __attribute__((address_space(3))) void* las_t;
__device__ __forceinline__ void gl_lds16(const void* g, void* l) {
    __builtin_amdgcn_global_load_lds((gas_t)g, (las_t)l, 16, 0, 0);
}

// ---------------- fp32 -> bf16 plain conversion (fcW) ----------------
__global__ __launch_bounds__(256)
void cvt_f2b_kernel(const float* __restrict__ s, unsigned short* __restrict__ d, int n4) {
    int i = blockIdx.x * 256 + threadIdx.x;
    if (i >= n4) return;
    float4 v = reinterpret_cast<const float4*>(s)[i];
    ushort4 o;
    o.x = f2bf(v.x); o.y = f2bf(v.y); o.z = f2bf(v.z); o.w = f2bf(v.w);
    reinterpret_cast<ushort4*>(d)[i] = o;
}

// ------- fp32 -> bf16 with gate-in-16-col-group permutation (K=1024 weights) -------
__global__ __launch_bounds__(256)
void cvt_perm_kernel(const float* __restrict__ s, unsigned short* __restrict__ d) {
    int i = blockIdx.x * 256 + threadIdx.x;     // over 4096 * 256 float4 groups
    int C  = i >> 8;                            // out row 0..4095
    int kk = i & 255;
    float4 v = reinterpret_cast<const float4*>(s)[(size_t)wrow_orig(C) * 256 + kk];
    ushort4 o;
    o.x = f2bf(v.x); o.y = f2bf(v.y); o.z = f2bf(v.z); o.w = f2bf(v.w);
    reinterpret_cast<ushort4*>(d)[(size_t)i] = o;
}

// ---------------- zero init (h0a,h1a bf16 + c0,c1 fp32 region, 24 MiB) ----------------
__global__ __launch_bounds__(256) void zero16_kernel(uint4* __restrict__ p) {
    uint4 z; z.x = 0; z.y = 0; z.z = 0; z.w = 0;
    p[(size_t)blockIdx.x * 256 + threadIdx.x] = z;
}

// ---------------- token matrix [2,S,B] ----------------
__global__ __launch_bounds__(256)
void tok_kernel(const int* __restrict__ src, const int* __restrict__ tgt, int* __restrict__ toks) {
    int idx = blockIdx.x * 256 + threadIdx.x;   // 2*24*2048
    int b  = idx & 2047;
    int st = idx >> 11;
    int tok;
    if (st < SS) tok = src[b * SS + st];
    else { int t = st - SS; tok = (t == 0) ? 1 : tgt[b * SS + (t - 1)]; }
    toks[idx] = tok;
}

// ---------------- per-layer bias sums, permuted layout ----------------
__global__ __launch_bounds__(256) void bias_sum_kernel(
        const float* e0i, const float* e0h, const float* e1i, const float* e1h,
        const float* d0i, const float* d0h, const float* d1i, const float* d1h,
        float* __restrict__ out) {
    int idx = blockIdx.x * 256 + threadIdx.x;   // 4*4096
    int layer = idx >> 12, C = idx & 4095;
    int src_j = wrow_orig(C);
    const float* pi; const float* ph;
    switch (layer) {
        case 0:  pi = e0i; ph = e0h; break;
        case 1:  pi = e1i; ph = e1h; break;
        case 2:  pi = d0i; ph = d0h; break;
        default: pi = d1i; ph = d1h; break;
    }
    out[idx] = pi[src_j] + ph[src_j];
}

// ---------------- fp32 input-projection tables: proj[table][v][C] ----------------
__global__ __launch_bounds__(256)
void proj_kernel(const float* __restrict__ emb, const float* __restrict__ eWih,
                 const float* __restrict__ dWih, float* __restrict__ proj) {
    // grid = 2 tables * 37 v * 16 C-blocks = 1184
    int bid = blockIdx.x;
    int table = bid / (VV * 16);
    int rem   = bid - table * (VV * 16);
    int v     = rem >> 4;
    int cblk  = rem & 15;
    const float* W = table ? dWih : eWih;
    __shared__ float es[EE];
    es[threadIdx.x] = emb[v * EE + threadIdx.x];
    __syncthreads();
    int C = (cblk << 8) + threadIdx.x;
    const float* wr = W + (size_t)wrow_orig(C) * EE;
    float acc = 0.f;
#pragma unroll 8
    for (int k = 0; k < EE; ++k) acc += es[k] * wr[k];
    proj[((size_t)table * VV + v) * G4H + C] = acc;
}

// ---------------- LSTM step GEMM + cell (r0-proven loop, BK=64, 4 blocks/CU) ----------
// gates[2048,4096] = A0 @ W0^T (+ A1 @ W1^T if nchunk=32) + bias (+ proj[tok] if prj)
// 128x128 tile, BK=64 (32 MFMA per drain), single 32 KB LDS buffer,
// in-register LSTM epilogue via gate-permuted W layout (no Gs, no bank conflicts).
__global__ __launch_bounds__(256, 4)
void lstm_step(const unsigned short* __restrict__ A0, const unsigned short* __restrict__ W0,
               const unsigned short* __restrict__ A1, const unsigned short* __restrict__ W1,
               int nchunk,
               const float* __restrict__ bias, const float* __restrict__ prj,
               const int* __restrict__ tok,
               float* __restrict__ cst, unsigned short* __restrict__ hout)
{
    __shared__ __align__(16) unsigned short As[8192];  // 8 tiles x 2 kc x 512 shorts = 16 KB
    __shared__ __align__(16) unsigned short Bs[8192];  // 16 KB

    const int tid  = threadIdx.x;
    const int lane = tid & 63;
    const int wave = tid >> 6;
    const int wm = wave >> 1, wn = wave & 1;
    const int m0 = blockIdx.y << 7;
    const int n0 = blockIdx.x << 7;

    const int r16  = lane & 15;
    const int koff = (lane >> 4) << 3;
    // global element offsets for the two 16-row tiles this wave stages (rows in 64-row halves)
    const unsigned aT0 = (unsigned)(m0 + (wave << 4) + r16) * HH + koff;
    const unsigned aT1 = aT0 + (unsigned)(64 * HH);
    const unsigned wT0 = (unsigned)(n0 + (wave << 4) + r16) * HH + koff;
    const unsigned wT1 = wT0 + (unsigned)(64 * HH);

    floatx4 acc[4][4];
#pragma unroll
    for (int i = 0; i < 4; ++i)
#pragma unroll
        for (int j = 0; j < 4; ++j)
            acc[i][j] = (floatx4){0.f, 0.f, 0.f, 0.f};

    for (int t = 0; t < nchunk; ++t) {
        const unsigned short* Ap = (t & 16) ? A1 : A0;
        const unsigned short* Wp = (t & 16) ? W1 : W0;
        const unsigned kk = (unsigned)(t & 15) << 6;          // k = (t%16)*64
        // stage 32 KB: tiles (wave, wave+4) x kc(0,1) for A and W — 8 loads/wave
        gl_lds16(Ap + aT0 + kk,      As + (wave << 10));
        gl_lds16(Ap + aT0 + kk + 32, As + (wave << 10) + 512);
        gl_lds16(Ap + aT1 + kk,      As + ((wave + 4) << 10));
        gl_lds16(Ap + aT1 + kk + 32, As + ((wave + 4) << 10) + 512);
        gl_lds16(Wp + wT0 + kk,      Bs + (wave << 10));
        gl_lds16(Wp + wT0 + kk + 32, Bs + (wave << 10) + 512);
        gl_lds16(Wp + wT1 + kk,      Bs + ((wave + 4) << 10));
        gl_lds16(Wp + wT1 + kk + 32, Bs + ((wave + 4) << 10) + 512);
        __syncthreads();               // drains vmcnt(0): staged data visible to all waves

#pragma unroll
        for (int kc = 0; kc < 2; ++kc) {
            short8 af[4], bfr[4];
#pragma unroll
            for (int i = 0; i < 4; ++i) {
                af[i]  = *reinterpret_cast<const short8*>(As + ((((wm << 2) + i) << 10) + (kc << 9) + (lane << 3)));
                bfr[i] = *reinterpret_cast<const short8*>(Bs + ((((wn << 2) + i) << 10) + (kc << 9) + (lane << 3)));
            }
#pragma unroll
            for (int i = 0; i < 4; ++i)
#pragma unroll
                for (int j = 0; j < 4; ++j)
                    acc[i][j] = __builtin_amdgcn_mfma_f32_16x16x32_bf16(af[i], bfr[j], acc[i][j], 0, 0, 0);
        }
        __syncthreads();               // readers done before next chunk overwrites
    }

    // ---- in-register LSTM cell epilogue ----
    // col C = n0 + wn*64 + j*16 + r16 -> gate j of unit ub (permuted W layout)
    const int q = lane >> 4;
    const int ub = (((n0 >> 6) + wn) << 4) + r16;
    float bj[4];
#pragma unroll
    for (int j = 0; j < 4; ++j)
        bj[j] = bias[n0 + (wn << 6) + (j << 4) + r16];

#pragma unroll
    for (int i = 0; i < 4; ++i) {
#pragma unroll
        for (int p = 0; p < 4; ++p) {
            const int row = m0 + (wm << 6) + (i << 4) + (q << 2) + p;
            float g0 = acc[i][0][p] + bj[0];
            float g1 = acc[i][1][p] + bj[1];
            float g2 = acc[i][2][p] + bj[2];
            float g3 = acc[i][3][p] + bj[3];
            if (prj != nullptr) {
                const float* pr = prj + (size_t)tok[row] * G4H + n0 + (wn << 6) + r16;
                g0 += pr[0]; g1 += pr[16]; g2 += pr[32]; g3 += pr[48];
            }
            const float iv = sigm(g0);
            const float fv = sigm(g1);
            const float gv = tanh_(g2);
            const float ov = sigm(g3);
            const size_t ci = (size_t)row * HH + ub;
            const float cc = fv * cst[ci] + iv * gv;
            cst[ci] = cc;
            hout[ci] = f2bf(ov * tanh_(cc));
        }
    }
}

// ---------------- FC head, one timestep ----------------
__global__ __launch_bounds__(256)
void fc_step_kernel(const unsigned short* __restrict__ h1, const unsigned short* __restrict__ fcW,
                    const float* __restrict__ fcb,
                    float* __restrict__ out, int t) {
    int b    = (blockIdx.x * 256 + threadIdx.x) >> 6;
    int lane = threadIdx.x & 63;
    if (lane >= VV) return;
    const unsigned short* hrow = h1 + (size_t)b * HH;
    const unsigned short* wrow = fcW + (size_t)lane * HH;
    float acc = fcb[lane];
#pragma unroll 4
    for (int k8 = 0; k8 < HH / 8; ++k8) {
        short8 hv = *reinterpret_cast<const short8*>(hrow + k8 * 8);
        short8 wv = *reinterpret_cast<const short8*>(wrow + k8 * 8);
#pragma unroll
        for (int uu = 0; uu < 8; ++uu)
            acc += bf2f((unsigned short)hv[uu]) * bf2f((unsigned short)wv[uu]);
    }
    out[(size_t)b * OSTR + t * VV + lane] = acc;
}

extern "C" void kernel_launch(void* const* d_in, const int* in_sizes, int n_in,
                              void* d_out, int out_size, void* d_ws, size_t ws_size,
                              hipStream_t stream) {
    const int*   src    = (const int*)d_in[0];
    const int*   tgt    = (const int*)d_in[1];
    const float* emb    = (const float*)d_in[2];
    const float* eW_ih0 = (const float*)d_in[3];
    const float* eW_hh0 = (const float*)d_in[4];
    const float* eb_ih0 = (const float*)d_in[5];
    const float* eb_hh0 = (const float*)d_in[6];
    const float* eW_ih1 = (const float*)d_in[7];
    const float* eW_hh1 = (const float*)d_in[8];
    const float* eb_ih1 = (const float*)d_in[9];
    const float* eb_hh1 = (const float*)d_in[10];
    const float* dW_ih0 = (const float*)d_in[11];
    const float* dW_hh0 = (const float*)d_in[12];
    const float* db_ih0 = (const float*)d_in[13];
    const float* db_hh0 = (const float*)d_in[14];
    const float* dW_ih1 = (const float*)d_in[15];
    const float* dW_hh1 = (const float*)d_in[16];
    const float* db_ih1 = (const float*)d_in[17];
    const float* db_hh1 = (const float*)d_in[18];
    const float* fcW    = (const float*)d_in[19];
    const float* fcb    = (const float*)d_in[20];
    float* out = (float*)d_out;

    // ---- workspace layout ----
    char* w = (char*)d_ws;
    size_t off = 0;
    auto walloc = [&](size_t bytes) { void* p = w + off; off += (bytes + 255) & ~(size_t)255; return p; };
    unsigned short* bW[8];
    const float* srcW[8] = {eW_ih0, eW_hh0, eW_ih1, eW_hh1, dW_ih0, dW_hh0, dW_ih1, dW_hh1};
    const int     szW[8] = {G4H*EE, G4H*HH, G4H*HH, G4H*HH, G4H*EE, G4H*HH, G4H*HH, G4H*HH};
    for (int i = 0; i < 8; ++i) bW[i] = (unsigned short*)walloc((size_t)szW[i] * 2);
    unsigned short* bfcW = (unsigned short*)walloc((size_t)VV * HH * 2);
    // zero region: h0a, h1a (bf16) + c0, c1 (fp32) — contiguous 24 MiB
    unsigned short* h0a = (unsigned short*)walloc((size_t)BB * HH * 2);
    unsigned short* h1a = (unsigned short*)walloc((size_t)BB * HH * 2);
    float* c0 = (float*)walloc((size_t)BB * HH * 4);
    float* c1 = (float*)walloc((size_t)BB * HH * 4);
    unsigned short* h0b = (unsigned short*)walloc((size_t)BB * HH * 2);
    unsigned short* h1b = (unsigned short*)walloc((size_t)BB * HH * 2);
    float* bsum = (float*)walloc((size_t)4 * G4H * 4);
    int*   toks = (int*)walloc((size_t)2 * SS * BB * 4);
    float* proj = (float*)walloc((size_t)2 * VV * G4H * 4);

    unsigned short* h0[2] = {h0a, h0b};
    unsigned short* h1[2] = {h1a, h1b};

    // ---- setup: permuted weights (K=1024 only; W_ih0 via proj), biases, tokens ----
    for (int i = 0; i < 8; ++i) {
        if (i == 0 || i == 4) continue;               // eW_ih0/dW_ih0: replaced by proj tables
        cvt_perm_kernel<<<(szW[i] / 4) / 256, 256, 0, stream>>>(srcW[i], bW[i]);
    }
    cvt_f2b_kernel<<<(VV * HH / 4 + 255) / 256, 256, 0, stream>>>(fcW, bfcW, VV * HH / 4);
    zero16_kernel<<<6144, 256, 0, stream>>>((uint4*)h0a);
    bias_sum_kernel<<<64, 256, 0, stream>>>(eb_ih0, eb_hh0, eb_ih1, eb_hh1,
                                            db_ih0, db_hh0, db_ih1, db_hh1, bsum);
    tok_kernel<<<384, 256, 0, stream>>>(src, tgt, toks);
    proj_kernel<<<2 * VV * 16, 256, 0, stream>>>(emb, eW_ih0, dW_ih0, proj);

    dim3 ggrid(G4H / 128, BB / 128);   // (32, 16) = 512 blocks

    int p = 0;
    for (int t = 0; t < 2 * SS; ++t) {
        const int enc = (t < SS);
        const unsigned short* Whh0 = enc ? bW[1] : bW[5];
        const unsigned short* Whh1 = enc ? bW[3] : bW[7];
        const unsigned short* Wih1 = enc ? bW[2] : bW[6];
        const float* b0 = bsum + (size_t)(enc ? 0 : 2) * G4H;
        const float* b1 = bsum + (size_t)(enc ? 1 : 3) * G4H;
        const float* pj = proj + (size_t)(enc ? 0 : 1) * VV * G4H;

        // L0: h0' = cell(h0 @ Whh0^T + proj[tok] + b0)   — 16 chunks (K=1024)
        lstm_step<<<ggrid, 256, 0, stream>>>(
            h0[p], Whh0, h0[p], Whh0, 16, b0, pj, toks + (size_t)t * BB, c0, h0[p ^ 1]);
        // L1: h1' = cell(h1 @ Whh1^T + h0' @ Wih1^T + b1) — 32 chunks (K=2048)
        lstm_step<<<ggrid, 256, 0, stream>>>(
            h1[p], Whh1, h0[p ^ 1], Wih1, 32, b1, nullptr, nullptr, c1, h1[p ^ 1]);
        if (!enc)
            fc_step_kernel<<<512, 256, 0, stream>>>(h1[p ^ 1], bfcW, fcb, out, t - SS);
        p ^= 1;
    }
}